// Round 2
// baseline (438.410 us; speedup 1.0000x reference)
//
#include <hip/hip_runtime.h>

// Bloch RK4 trajectory integrator — round 2.
// One thread per system, state in registers. Output staged in LDS in groups
// of 4 time steps, then flushed with fully-coalesced float4 stores (each
// wave-store = 1 KB dense). Double-buffered LDS: one barrier per 4 steps.
//
// Round-1 post-mortem: scalar stride-12B stores ran at ~1 TB/s effective
// (403 us) — 12 partial cache lines per store inst, each 64B line touched by
// 3 different insts. This round targets the ~6.2 TB/s write ceiling the
// harness's fillBuffer achieves (~65 us floor for 402.7 MB).

#define NB 65536
#define NT 512
#define B3 (NB * 3)

__global__ __launch_bounds__(256) void bloch_rk4_kernel(
    const float* __restrict__ y0,
    const float* __restrict__ tspan,
    const float* __restrict__ params,
    float* __restrict__ out)
{
    __shared__ float sdt[NT];          // sdt[i] = tspan[i+1]-tspan[i]; sdt[NT-1]=0 pad
    __shared__ float buf[2][4 * 768];  // 2 x (4 steps x 256 systems x 3) = 24 KB

    const int tid = threadIdx.x;
    for (int i = tid; i < NT; i += 256) {
        float d = 0.0f;
        if (i < NT - 1) d = tspan[i + 1] - tspan[i];
        sdt[i] = d;
    }
    __syncthreads();

    const int S   = blockIdx.x * 256;   // first system of this block
    const int b   = S + tid;
    const int ib3 = b * 3;

    float u = y0[ib3 + 0];
    float v = y0[ib3 + 1];
    float w = y0[ib3 + 2];
    const float Om = params[ib3 + 0];
    const float g  = params[ib3 + 2];
    const float g2 = 2.0f * g;

    int p = 0;
    // slot 0 of group 0 is y0 itself
    {
        float* bp = &buf[p][tid * 3];
        bp[0] = u; bp[1] = v; bp[2] = w;
    }

    float dt = sdt[0];
    for (int t = 1; t < NT; ++t) {
        const float dt_next = sdt[t];   // prefetch (broadcast, hidden behind compute)

        // ---- RK4 step ----
        const float k1u = -g * u;
        const float k1v = -g * v - Om * w;
        const float k1w = Om * v - g2 * w - g2;

        const float h = 0.5f * dt;
        float uu = u + h * k1u;
        float vv = v + h * k1v;
        float ww = w + h * k1w;

        const float k2u = -g * uu;
        const float k2v = -g * vv - Om * ww;
        const float k2w = Om * vv - g2 * ww - g2;

        uu = u + h * k2u;
        vv = v + h * k2v;
        ww = w + h * k2w;

        const float k3u = -g * uu;
        const float k3v = -g * vv - Om * ww;
        const float k3w = Om * vv - g2 * ww - g2;

        uu = u + dt * k3u;
        vv = v + dt * k3v;
        ww = w + dt * k3w;

        const float k4u = -g * uu;
        const float k4v = -g * vv - Om * ww;
        const float k4w = Om * vv - g2 * ww - g2;

        const float s6 = dt * (1.0f / 6.0f);
        u += s6 * (k1u + 2.0f * k2u + 2.0f * k3u + k4u);
        v += s6 * (k1v + 2.0f * k2v + 2.0f * k3v + k4v);
        w += s6 * (k1w + 2.0f * k2w + 2.0f * k3w + k4w);

        // ---- stash into LDS ----
        const int s = t & 3;
        {
            float* bp = &buf[p][s * 768 + tid * 3];
            bp[0] = u; bp[1] = v; bp[2] = w;
        }

        // ---- flush 4 staged steps with coalesced float4 stores ----
        if (s == 3) {
            __syncthreads();
            const float4* src = (const float4*)buf[p];
            const int t0 = t - 3;
            #pragma unroll
            for (int k = 0; k < 3; ++k) {
                const int j  = tid + k * 256;   // 0..767 float4 across the group
                const int ss = j / 192;         // which of the 4 steps (192 f4 each)
                const int r  = j - ss * 192;    // f4 index within that step's region
                float4* dst = (float4*)(out + (size_t)(t0 + ss) * B3 + S * 3);
                dst[r] = src[j];
            }
            p ^= 1;
        }

        dt = dt_next;
    }
}

extern "C" void kernel_launch(void* const* d_in, const int* in_sizes, int n_in,
                              void* d_out, int out_size, void* d_ws, size_t ws_size,
                              hipStream_t stream) {
    const float* y0     = (const float*)d_in[0];
    const float* tspan  = (const float*)d_in[1];
    const float* params = (const float*)d_in[2];
    float* out = (float*)d_out;

    bloch_rk4_kernel<<<NB / 256, 256, 0, stream>>>(y0, tspan, params, out);
}